// Round 1
// baseline (405.763 us; speedup 1.0000x reference)
//
#include <hip/hip_runtime.h>

// GCN: out[m,n,o] = (A_hat relu(A_hat (x W1) + b1) W_out[m])[n,o] + b_out[m,o]
// A_hat = D^-1/2 (A + I) D^-1/2, edges dst-grouped via CSR built per call.
// Trick: propagate-2 runs on the 8-col projection (propagation is linear in features).

constexpr int CIN = 128;

// ---------- graph prep ----------
__global__ void hist_k(const int* __restrict__ dst, int* __restrict__ cnt, int E) {
  int i = blockIdx.x * blockDim.x + threadIdx.x;
  if (i < E) atomicAdd(&cnt[dst[i]], 1);
}

__global__ void dinv_k(const int* __restrict__ cnt, float* __restrict__ dinv, int n) {
  int i = blockIdx.x * blockDim.x + threadIdx.x;
  if (i < n) dinv[i] = 1.0f / sqrtf((float)(cnt[i] + 1));  // +1 self-loop, always > 0
}

// exclusive scan of a <=256*256 array chunk-wise; btot==nullptr for the top-level pass
__global__ __launch_bounds__(256) void scan_k(const int* __restrict__ v_in,
    int* __restrict__ excl_out, int* __restrict__ btot, int n) {
  __shared__ int wsum[4];
  int t = threadIdx.x, l = t & 63, w = t >> 6;
  int i = blockIdx.x * 256 + t;
  int v = (i < n) ? v_in[i] : 0;
  int orig = v;
  #pragma unroll
  for (int off = 1; off < 64; off <<= 1) {
    int u = __shfl_up(v, off);
    if (l >= off) v += u;
  }
  if (l == 63) wsum[w] = v;
  __syncthreads();
  int add = 0;
  #pragma unroll
  for (int j = 0; j < 4; ++j) if (j < w) add += wsum[j];
  v += add;
  if (i < n) excl_out[i] = v - orig;
  if (t == 255 && btot != nullptr) btot[blockIdx.x] = v;
}

__global__ void scan_fix_k(int* __restrict__ row_ptr, int* __restrict__ fill,
                           const int* __restrict__ boff, int n, int E) {
  int i = blockIdx.x * 256 + threadIdx.x;
  if (i < n) {
    int v = row_ptr[i] + boff[blockIdx.x];
    row_ptr[i] = v;
    fill[i] = v;
  }
  if (i == n) row_ptr[n] = E;
}

__global__ void scatter_k(const int* __restrict__ src, const int* __restrict__ dst,
                          int* __restrict__ fill, int* __restrict__ csr, int E) {
  int i = blockIdx.x * blockDim.x + threadIdx.x;
  if (i < E) {
    int p = atomicAdd(&fill[dst[i]], 1);
    csr[p] = src[i];
  }
}

// ---------- g = dinv[n] * (x @ W1), fp32 LDS-tiled ----------
__global__ __launch_bounds__(256) void gemm_k(const float* __restrict__ x,
    const float* __restrict__ W, const float* __restrict__ dinv,
    float* __restrict__ g, int nrows) {
  __shared__ float As[32][132];  // [k][row], padded
  __shared__ float Bs[32][132];  // [k][col], padded
  int t = threadIdx.x;
  int tx = t & 15, ty = t >> 4;
  int row0 = blockIdx.x * 128;
  float acc[8][8];
  #pragma unroll
  for (int i = 0; i < 8; ++i)
    #pragma unroll
    for (int j = 0; j < 8; ++j) acc[i][j] = 0.f;

  for (int kc = 0; kc < 4; ++kc) {
    int k0 = kc * 32;
    #pragma unroll
    for (int i = 0; i < 4; ++i) {          // A: 128 rows x 32 k, transpose to [k][row]
      int q = t + 256 * i;                  // 0..1023 float4s
      int kq = q & 7;                       // float4 index in k
      int r  = q >> 3;                      // row 0..127
      int grow = row0 + r;
      float4 v = make_float4(0.f, 0.f, 0.f, 0.f);
      if (grow < nrows) v = *(const float4*)&x[grow * CIN + k0 + 4 * kq];
      As[4 * kq + 0][r] = v.x; As[4 * kq + 1][r] = v.y;
      As[4 * kq + 2][r] = v.z; As[4 * kq + 3][r] = v.w;
    }
    #pragma unroll
    for (int i = 0; i < 4; ++i) {          // B: 32 k x 128 cols
      int q = t + 256 * i;
      int c4 = q & 31;
      int k  = q >> 5;
      float4 v = *(const float4*)&W[(k0 + k) * CIN + 4 * c4];
      *(float4*)&Bs[k][4 * c4] = v;
    }
    __syncthreads();
    #pragma unroll
    for (int k = 0; k < 32; ++k) {
      float a[8], b[8];
      *(float4*)&a[0] = *(const float4*)&As[k][4 * ty];
      *(float4*)&a[4] = *(const float4*)&As[k][64 + 4 * ty];
      *(float4*)&b[0] = *(const float4*)&Bs[k][4 * tx];
      *(float4*)&b[4] = *(const float4*)&Bs[k][64 + 4 * tx];
      #pragma unroll
      for (int i = 0; i < 8; ++i)
        #pragma unroll
        for (int j = 0; j < 8; ++j) acc[i][j] = fmaf(a[i], b[j], acc[i][j]);
    }
    __syncthreads();
  }
  #pragma unroll
  for (int i = 0; i < 8; ++i) {
    int r = (i < 4) ? (4 * ty + i) : (64 + 4 * ty + (i - 4));
    int grow = row0 + r;
    if (grow < nrows) {
      float dv = dinv[grow];
      float4 o0 = make_float4(acc[i][0] * dv, acc[i][1] * dv, acc[i][2] * dv, acc[i][3] * dv);
      float4 o1 = make_float4(acc[i][4] * dv, acc[i][5] * dv, acc[i][6] * dv, acc[i][7] * dv);
      *(float4*)&g[grow * CIN + 4 * tx] = o0;
      *(float4*)&g[grow * CIN + 64 + 4 * tx] = o1;
    }
  }
}

// ---------- propagate-1 fused: relu(dinv*(self+gather)+b1) projected to 8 cols ----------
__global__ __launch_bounds__(256) void prop1_k(const float* __restrict__ g,
    const int* __restrict__ row_ptr, const int* __restrict__ csr,
    const float* __restrict__ dinv, const float* __restrict__ b1,
    const float* __restrict__ Wout, float* __restrict__ g2,
    int n_nodes, int n_waves) {
  int l = threadIdx.x & 63;
  int wid = (blockIdx.x * blockDim.x + threadIdx.x) >> 6;
  // per-lane W_cat rows 2l, 2l+1: W_cat[k][j] = Wout[(j>>1)*256 + k*2 + (j&1)]
  float w0[8], w1[8];
  #pragma unroll
  for (int j = 0; j < 8; ++j) {
    w0[j] = Wout[(j >> 1) * 256 + 4 * l + (j & 1)];
    w1[j] = Wout[(j >> 1) * 256 + 4 * l + 2 + (j & 1)];
  }
  float2 bb = *(const float2*)&b1[2 * l];
  const float* gl = g + 2 * l;

  for (int n = wid; n < n_nodes; n += n_waves) {
    int start = row_ptr[n], end = row_ptr[n + 1];
    float d = dinv[n];
    float2 acc = *(const float2*)&gl[n * CIN];  // self-loop term (dinv folded in g)
    for (int base = start; base < end; base += 64) {
      int cnt = min(64, end - base);
      int eb = (base + l < end) ? csr[base + l] : 0;
      int i = 0;
      for (; i + 4 <= cnt; i += 4) {
        int s0 = __shfl(eb, i), s1 = __shfl(eb, i + 1);
        int s2 = __shfl(eb, i + 2), s3 = __shfl(eb, i + 3);
        float2 v0 = *(const float2*)&gl[s0 * CIN];
        float2 v1 = *(const float2*)&gl[s1 * CIN];
        float2 v2 = *(const float2*)&gl[s2 * CIN];
        float2 v3 = *(const float2*)&gl[s3 * CIN];
        acc.x += (v0.x + v1.x) + (v2.x + v3.x);
        acc.y += (v0.y + v1.y) + (v2.y + v3.y);
      }
      for (; i < cnt; ++i) {
        int s = __shfl(eb, i);
        float2 v = *(const float2*)&gl[s * CIN];
        acc.x += v.x; acc.y += v.y;
      }
    }
    float y0 = fmaxf(fmaf(acc.x, d, bb.x), 0.f);
    float y1 = fmaxf(fmaf(acc.y, d, bb.y), 0.f);
    float p[8];
    #pragma unroll
    for (int j = 0; j < 8; ++j) p[j] = fmaf(y0, w0[j], y1 * w1[j]);
    #pragma unroll
    for (int off = 1; off < 64; off <<= 1)
      #pragma unroll
      for (int j = 0; j < 8; ++j) p[j] += __shfl_xor(p[j], off);
    if (l < 8) {
      float v = (l == 0) ? p[0] : (l == 1) ? p[1] : (l == 2) ? p[2] : (l == 3) ? p[3]
              : (l == 4) ? p[4] : (l == 5) ? p[5] : (l == 6) ? p[6] : p[7];
      g2[n * 8 + l] = d * v;
    }
  }
}

// ---------- propagate-2 on 8 cols + bias, writes d_out ----------
__global__ __launch_bounds__(256) void prop2_k(const float* __restrict__ g2,
    const int* __restrict__ row_ptr, const int* __restrict__ csr,
    const float* __restrict__ dinv, const float* __restrict__ bout,
    float* __restrict__ out, int n_nodes, int n_groups) {
  int tid = blockIdx.x * blockDim.x + threadIdx.x;
  int gidx = tid >> 3;
  int f = tid & 7;
  float bo = bout[f];
  for (int n = gidx; n < n_nodes; n += n_groups) {
    int start = row_ptr[n], end = row_ptr[n + 1];
    float acc = g2[n * 8 + f];  // self-loop
    for (int e = start; e < end; ++e) {
      int s = csr[e];
      acc += g2[s * 8 + f];
    }
    out[(f >> 1) * (2 * n_nodes) + n * 2 + (f & 1)] = fmaf(dinv[n], acc, bo);
  }
}

extern "C" void kernel_launch(void* const* d_in, const int* in_sizes, int n_in,
                              void* d_out, int out_size, void* d_ws, size_t ws_size,
                              hipStream_t stream) {
  const float* x    = (const float*)d_in[0];
  const int*   ei   = (const int*)d_in[1];
  const float* W1   = (const float*)d_in[2];
  const float* b1   = (const float*)d_in[3];
  const float* Wout = (const float*)d_in[4];
  const float* bout = (const float*)d_in[5];
  float* out = (float*)d_out;

  const int N = in_sizes[0] / CIN;     // 50000
  const int E = in_sizes[1] / 2;       // 1600000
  const int* srcp = ei;
  const int* dstp = ei + E;

  char* ws = (char*)d_ws;
  size_t off = 0;
  auto alloc = [&](size_t bytes) -> void* {
    void* p = ws + off;
    off = (off + bytes + 511) & ~(size_t)511;
    return p;
  };
  float* g       = (float*)alloc((size_t)N * CIN * 4);
  float* g2      = (float*)alloc((size_t)N * 8 * 4);
  float* dinv    = (float*)alloc((size_t)N * 4);
  int*   cnt     = (int*)alloc((size_t)N * 4);
  int*   row_ptr = (int*)alloc((size_t)(N + 1) * 4);
  int*   fill    = (int*)alloc((size_t)N * 4);
  int*   btot    = (int*)alloc(256 * 4);
  int*   boff    = (int*)alloc(256 * 4);
  int*   csr     = (int*)alloc((size_t)E * 4);
  (void)ws_size; (void)n_in; (void)out_size;

  const int NB = (N + 255) / 256;      // 196 scan blocks (<=256)
  hipMemsetAsync(cnt, 0, (size_t)N * 4, stream);
  hist_k<<<(E + 255) / 256, 256, 0, stream>>>(dstp, cnt, E);
  dinv_k<<<NB, 256, 0, stream>>>(cnt, dinv, N);
  scan_k<<<NB, 256, 0, stream>>>(cnt, row_ptr, btot, N);
  scan_k<<<1, 256, 0, stream>>>(btot, boff, nullptr, NB);
  scan_fix_k<<<NB, 256, 0, stream>>>(row_ptr, fill, boff, N, E);
  scatter_k<<<(E + 255) / 256, 256, 0, stream>>>(srcp, dstp, fill, csr, E);

  gemm_k<<<(N + 127) / 128, 256, 0, stream>>>(x, W1, dinv, g, N);

  const int P1_BLOCKS = 2048;
  prop1_k<<<P1_BLOCKS, 256, 0, stream>>>(g, row_ptr, csr, dinv, b1, Wout, g2,
                                         N, P1_BLOCKS * 4);
  const int P2_BLOCKS = 512;
  prop2_k<<<P2_BLOCKS, 256, 0, stream>>>(g2, row_ptr, csr, dinv, bout, out,
                                         N, P2_BLOCKS * 32);
}